// Round 4
// baseline (251.117 us; speedup 1.0000x reference)
//
#include <hip/hip_runtime.h>
#include <stdint.h>

#define Bn 16384
#define Dn 64
#define Hn 256

typedef short bf16x8 __attribute__((ext_vector_type(8)));
typedef float f32x4 __attribute__((ext_vector_type(4)));

__device__ __forceinline__ unsigned f2bf1(float f) {
  unsigned u = __float_as_uint(f);
  return (u + 0x7FFFu + ((u >> 16) & 1u)) >> 16;   // RNE to bf16
}

// ---------- pack W2 (fp32 [D][H][H]) into MFMA B-fragment-linear bf16 ----------
// layout: [d][kk(8)][nj(16)][lane(64)][8 bf16]; lane holds B[k=kk*32+(lane>>4)*8+b][n=nj*16+(lane&15)]
__global__ __launch_bounds__(256) void pack_w2(const float* __restrict__ W2,
                                               unsigned short* __restrict__ Bp) {
  int g = blockIdx.x * 4 + (threadIdx.x >> 6);   // 8192 units
  int lane = threadIdx.x & 63;
  int d  = g >> 7;
  int kk = (g >> 4) & 7;
  int nj = g & 15;
  int k0 = kk * 32 + ((lane >> 4) << 3);
  int n  = nj * 16 + (lane & 15);
  const float* src = W2 + ((size_t)d * Hn + k0) * Hn + n;
  unsigned t[8];
  #pragma unroll
  for (int b = 0; b < 8; ++b) t[b] = f2bf1(src[(size_t)b * Hn]);
  uint4 w;
  w.x = t[0] | (t[1] << 16);
  w.y = t[2] | (t[3] << 16);
  w.z = t[4] | (t[5] << 16);
  w.w = t[6] | (t[7] << 16);
  size_t off = (((size_t)g) * 64 + lane) * 8;    // elements
  *(uint4*)(Bp + off) = w;
}

// ---------- transpose small tail weights for coalesced reads ----------
__global__ __launch_bounds__(256) void prep_t(
    const float* __restrict__ Wq, const float* __restrict__ Wk,
    const float* __restrict__ Wc1, const float* __restrict__ Ws,
    float* __restrict__ WqT, float* __restrict__ WkT,
    float* __restrict__ Wc1T, float* __restrict__ WsT) {
  int t = blockIdx.x * 256 + threadIdx.x;   // 16384
  int h = t >> 6, dd = t & 63;
  WqT[dd * 256 + h]  = Wq[h * 64 + dd];
  WkT[dd * 256 + h]  = Wk[h * 64 + dd];
  Wc1T[dd * 256 + h] = Wc1[h * 64 + dd];
  WsT[h * 64 + dd]   = Ws[dd * 256 + h];
}

// ---------- main fused kernel: LDS-free, barrier-free K-loop ----------
// 256 threads = 4 waves in 2M x 2N: each wave owns 32 rows x 128 cols.
// A (a1) computed in registers (2 mi frags/wave -> only 2x M-duplication).
// B fragments loaded global(L2) -> regs from fragment-linear Bp, 1-stage prefetch.
__global__ __launch_bounds__(256, 3) void gemm_hcat(
    const float* __restrict__ x, const float* __restrict__ W1,
    const float* __restrict__ b1, const float* __restrict__ b2,
    const float* __restrict__ W3, const float* __restrict__ b3,
    const unsigned short* __restrict__ Bp, float* __restrict__ hcT) {
  __shared__ float P[2][64];

  int bid = blockIdx.x;
  int swz = (bid & 7) * 2048 + (bid >> 3);   // bijective XCD swizzle (16384 = 8*2048)
  int d = swz >> 8;
  int m0 = (swz & 255) << 6;

  int tid = threadIdx.x;
  int lane = tid & 63;
  int wid = tid >> 6;
  int wm = wid >> 1, wn = wid & 1;           // 2M x 2N waves, 32x128 per wave
  int l15 = lane & 15;
  int koct = (lane >> 4) << 3;

  const unsigned short* BpD = Bp + (size_t)d * 65536;
  const float* W1d = W1 + d * Hn;
  const float* b1d = b1 + d * Hn;

  float xr[2];
  #pragma unroll
  for (int mi = 0; mi < 2; ++mi)
    xr[mi] = x[(size_t)(m0 + (wm << 5) + mi * 16 + l15) * Dn + d];

  f32x4 acc[2][8] = {};

  #define LOADB(s, dst)                                                         \
    _Pragma("unroll")                                                           \
    for (int nj = 0; nj < 8; ++nj)                                              \
      dst[nj] = *(const bf16x8*)(BpD + ((((s) * 16 + (wn << 3) + nj) << 6) + lane) * 8);

  bf16x8 bcur[8];
  LOADB(0, bcur);

  #pragma unroll
  for (int s = 0; s < 8; ++s) {
    bf16x8 bnxt[8];
    if (s < 7) { LOADB(s + 1, bnxt); }

    // a1 fragments: af[mi][j] = bf16(relu(xr[mi]*W1[k+j]+b1[k+j])), RNE via cvt_pk
    int k = s * 32 + koct;
    float4 wa = *(const float4*)(W1d + k);
    float4 wb = *(const float4*)(W1d + k + 4);
    float4 ba = *(const float4*)(b1d + k);
    float4 bb = *(const float4*)(b1d + k + 4);
    bf16x8 af[2];
    #pragma unroll
    for (int mi = 0; mi < 2; ++mi) {
      float xv = xr[mi];
      float v0 = fmaxf(fmaf(xv, wa.x, ba.x), 0.f);
      float v1 = fmaxf(fmaf(xv, wa.y, ba.y), 0.f);
      float v2 = fmaxf(fmaf(xv, wa.z, ba.z), 0.f);
      float v3 = fmaxf(fmaf(xv, wa.w, ba.w), 0.f);
      float v4 = fmaxf(fmaf(xv, wb.x, bb.x), 0.f);
      float v5 = fmaxf(fmaf(xv, wb.y, bb.y), 0.f);
      float v6 = fmaxf(fmaf(xv, wb.z, bb.z), 0.f);
      float v7 = fmaxf(fmaf(xv, wb.w, bb.w), 0.f);
      union { uint4 u; bf16x8 v; } pk;
      asm("v_cvt_pk_bf16_f32 %0, %1, %2" : "=v"(pk.u.x) : "v"(v0), "v"(v1));
      asm("v_cvt_pk_bf16_f32 %0, %1, %2" : "=v"(pk.u.y) : "v"(v2), "v"(v3));
      asm("v_cvt_pk_bf16_f32 %0, %1, %2" : "=v"(pk.u.z) : "v"(v4), "v"(v5));
      asm("v_cvt_pk_bf16_f32 %0, %1, %2" : "=v"(pk.u.w) : "v"(v6), "v"(v7));
      af[mi] = pk.v;
    }

    __builtin_amdgcn_s_setprio(1);
    #pragma unroll
    for (int mi = 0; mi < 2; ++mi)
      #pragma unroll
      for (int nj = 0; nj < 8; ++nj)
        acc[mi][nj] = __builtin_amdgcn_mfma_f32_16x16x32_bf16(af[mi], bcur[nj], acc[mi][nj], 0, 0, 0);
    __builtin_amdgcn_s_setprio(0);

    if (s < 7) {
      #pragma unroll
      for (int nj = 0; nj < 8; ++nj) bcur[nj] = bnxt[nj];
    }
  }

  // epilogue: relu(+b2) . W3 over this wave's 128 columns, then cross-wn reduce
  {
    const float* b2d = b2 + d * Hn;
    const float* W3d = W3 + d * Hn;
    float bv[8], wv[8];
    #pragma unroll
    for (int nj = 0; nj < 8; ++nj) {
      int col = (wn << 7) + nj * 16 + l15;
      bv[nj] = b2d[col];
      wv[nj] = W3d[col];
    }
    #pragma unroll
    for (int mi = 0; mi < 2; ++mi) {
      #pragma unroll
      for (int i = 0; i < 4; ++i) {
        float sv = 0.f;
        #pragma unroll
        for (int nj = 0; nj < 8; ++nj)
          sv += fmaxf(acc[mi][nj][i] + bv[nj], 0.f) * wv[nj];
        sv += __shfl_xor(sv, 1);
        sv += __shfl_xor(sv, 2);
        sv += __shfl_xor(sv, 4);
        sv += __shfl_xor(sv, 8);
        if (l15 == 0)
          P[wn][(wm << 5) + (mi << 4) + ((lane >> 4) << 2) + i] = sv;
      }
    }
  }
  __syncthreads();
  if (tid < 64)
    hcT[(size_t)d * Bn + m0 + tid] = P[0][tid] + P[1][tid] + b3[d];
}

// ---------- tail: attention fusion + cross MLP + g_func; 4 rows per wave ----------
__global__ __launch_bounds__(256) void fused_tail(
    const float* __restrict__ hcT, const float* __restrict__ WqT,
    const float* __restrict__ bq, const float* __restrict__ WkT,
    const float* __restrict__ bk, const float* __restrict__ WsT,
    const float* __restrict__ bs, const float* __restrict__ Wc1T,
    const float* __restrict__ bc1, const float* __restrict__ Wc2,
    const float* __restrict__ bc2, const float* __restrict__ Wg1,
    const float* __restrict__ bg1, const float* __restrict__ Wg2,
    const float* __restrict__ bg2, float* __restrict__ out) {
  __shared__ float hcs[4][4][64];
  __shared__ float ts[4][4][256];
  int wid = threadIdx.x >> 6;
  int lane = threadIdx.x & 63;
  int r0 = (blockIdx.x * 4 + wid) * 4;                 // 4 rows per wave
  float4 hc4 = *(const float4*)(hcT + (size_t)lane * Bn + r0);   // lane <-> feature d
  hcs[wid][0][lane] = hc4.x;
  hcs[wid][1][lane] = hc4.y;
  hcs[wid][2][lane] = hc4.z;
  hcs[wid][3][lane] = hc4.w;
  __syncthreads();

  float qv[4][4], kv[4][4], cv[4][4];
  #pragma unroll
  for (int j = 0; j < 4; ++j) {
    int h = lane + 64 * j;
    float bqv = bq[h], bkv = bk[h], bcv = bc1[h];
    #pragma unroll
    for (int r = 0; r < 4; ++r) { qv[r][j] = bqv; kv[r][j] = bkv; cv[r][j] = bcv; }
  }
  for (int d2 = 0; d2 < 64; ++d2) {
    float hv0 = hcs[wid][0][d2], hv1 = hcs[wid][1][d2];
    float hv2 = hcs[wid][2][d2], hv3 = hcs[wid][3][d2];
    #pragma unroll
    for (int j = 0; j < 4; ++j) {
      int h = lane + 64 * j;
      float wq = WqT[d2 * 256 + h], wk = WkT[d2 * 256 + h], wc = Wc1T[d2 * 256 + h];
      qv[0][j] = fmaf(wq, hv0, qv[0][j]); qv[1][j] = fmaf(wq, hv1, qv[1][j]);
      qv[2][j] = fmaf(wq, hv2, qv[2][j]); qv[3][j] = fmaf(wq, hv3, qv[3][j]);
      kv[0][j] = fmaf(wk, hv0, kv[0][j]); kv[1][j] = fmaf(wk, hv1, kv[1][j]);
      kv[2][j] = fmaf(wk, hv2, kv[2][j]); kv[3][j] = fmaf(wk, hv3, kv[3][j]);
      cv[0][j] = fmaf(wc, hv0, cv[0][j]); cv[1][j] = fmaf(wc, hv1, cv[1][j]);
      cv[2][j] = fmaf(wc, hv2, cv[2][j]); cv[3][j] = fmaf(wc, hv3, cv[3][j]);
    }
  }
  #pragma unroll
  for (int r = 0; r < 4; ++r)
    #pragma unroll
    for (int j = 0; j < 4; ++j)
      ts[wid][r][lane + 64 * j] = tanhf(qv[r][j] * kv[r][j]);
  __syncthreads();

  float sc[4];
  { float b = bs[lane]; sc[0] = b; sc[1] = b; sc[2] = b; sc[3] = b; }
  for (int h2 = 0; h2 < 256; ++h2) {
    float w = WsT[h2 * 64 + lane];
    sc[0] = fmaf(w, ts[wid][0][h2], sc[0]);
    sc[1] = fmaf(w, ts[wid][1][h2], sc[1]);
    sc[2] = fmaf(w, ts[wid][2][h2], sc[2]);
    sc[3] = fmaf(w, ts[wid][3][h2], sc[3]);
  }

  float hcr[4] = {hc4.x, hc4.y, hc4.z, hc4.w};
  float res[4];
  #pragma unroll
  for (int r = 0; r < 4; ++r) {
    float s = sc[r];
    float mx = s;
    #pragma unroll
    for (int off = 1; off < 64; off <<= 1) mx = fmaxf(mx, __shfl_xor(mx, off));
    float e = __expf(s - mx);
    float se = e;
    #pragma unroll
    for (int off = 1; off < 64; off <<= 1) se += __shfl_xor(se, off);
    float wgt = hcr[r] * (e / se);
    #pragma unroll
    for (int off = 1; off < 64; off <<= 1) wgt += __shfl_xor(wgt, off);
    float cp = 0.f;
    #pragma unroll
    for (int j = 0; j < 4; ++j) cp = fmaf(fmaxf(cv[r][j], 0.f), Wc2[lane + 64 * j], cp);
    #pragma unroll
    for (int off = 1; off < 64; off <<= 1) cp += __shfl_xor(cp, off);
    float comb = wgt + cp + bc2[0];
    float fp = 0.f;
    #pragma unroll
    for (int j = 0; j < 4; ++j) {
      int h = lane + 64 * j;
      fp = fmaf(fmaxf(fmaf(comb, Wg1[h], bg1[h]), 0.f), Wg2[h], fp);
    }
    #pragma unroll
    for (int off = 1; off < 64; off <<= 1) fp += __shfl_xor(fp, off);
    res[r] = fp + bg2[0];
  }
  if (lane == 0) {
    float4 o = make_float4(res[0], res[1], res[2], res[3]);
    *(float4*)(out + r0) = o;
  }
}

extern "C" void kernel_launch(void* const* d_in, const int* in_sizes, int n_in,
                              void* d_out, int out_size, void* d_ws, size_t ws_size,
                              hipStream_t stream) {
  const float* x   = (const float*)d_in[0];
  const float* W1  = (const float*)d_in[1];
  const float* b1  = (const float*)d_in[2];
  const float* W2  = (const float*)d_in[3];
  const float* b2  = (const float*)d_in[4];
  const float* W3  = (const float*)d_in[5];
  const float* b3  = (const float*)d_in[6];
  const float* Wq  = (const float*)d_in[7];
  const float* bq  = (const float*)d_in[8];
  const float* Wk  = (const float*)d_in[9];
  const float* bk  = (const float*)d_in[10];
  const float* Ws  = (const float*)d_in[11];
  const float* bs  = (const float*)d_in[12];
  const float* Wc1 = (const float*)d_in[13];
  const float* bc1 = (const float*)d_in[14];
  const float* Wc2 = (const float*)d_in[15];
  const float* bc2 = (const float*)d_in[16];
  const float* Wg1 = (const float*)d_in[17];
  const float* bg1 = (const float*)d_in[18];
  const float* Wg2 = (const float*)d_in[19];
  const float* bg2 = (const float*)d_in[20];

  unsigned short* Bp = (unsigned short*)d_ws;               // 8,388,608 B
  float* hcT  = (float*)((char*)d_ws + 8388608);            // 4,194,304 B
  float* WqT  = (float*)((char*)d_ws + 12582912);
  float* WkT  = WqT + 16384;
  float* Wc1T = WkT + 16384;
  float* WsT  = Wc1T + 16384;

  pack_w2<<<2048, 256, 0, stream>>>(W2, Bp);
  prep_t<<<64, 256, 0, stream>>>(Wq, Wk, Wc1, Ws, WqT, WkT, Wc1T, WsT);
  gemm_hcat<<<16384, 256, 0, stream>>>(x, W1, b1, b2, W3, b3, Bp, hcT);
  fused_tail<<<1024, 256, 0, stream>>>(hcT, WqT, bq, WkT, bk, WsT, bs, Wc1T, bc1,
                                       Wc2, bc2, Wg1, bg1, Wg2, bg2, (float*)d_out);
}

// Round 5
// 217.094 us; speedup vs baseline: 1.1567x; 1.1567x over previous
//
#include <hip/hip_runtime.h>
#include <stdint.h>

#define Bn 16384
#define Dn 64
#define Hn 256

typedef short bf16x8 __attribute__((ext_vector_type(8)));
typedef float f32x4 __attribute__((ext_vector_type(4)));

__device__ __forceinline__ unsigned f2bf1(float f) {
  unsigned u = __float_as_uint(f);
  return (u + 0x7FFFu + ((u >> 16) & 1u)) >> 16;   // RNE to bf16
}

// ---------- pack W2 (fp32 [D][H][H]) into MFMA B-fragment-linear bf16 ----------
// layout: [d][kk(8)][nj(16)][lane(64)][8 bf16]; lane holds B[k=kk*32+(lane>>4)*8+b][n=nj*16+(lane&15)]
__global__ __launch_bounds__(256) void pack_w2(const float* __restrict__ W2,
                                               unsigned short* __restrict__ Bp) {
  int g = blockIdx.x * 4 + (threadIdx.x >> 6);   // 8192 units
  int lane = threadIdx.x & 63;
  int d  = g >> 7;
  int kk = (g >> 4) & 7;
  int nj = g & 15;
  int k0 = kk * 32 + ((lane >> 4) << 3);
  int n  = nj * 16 + (lane & 15);
  const float* src = W2 + ((size_t)d * Hn + k0) * Hn + n;
  unsigned t[8];
  #pragma unroll
  for (int b = 0; b < 8; ++b) t[b] = f2bf1(src[(size_t)b * Hn]);
  uint4 w;
  w.x = t[0] | (t[1] << 16);
  w.y = t[2] | (t[3] << 16);
  w.z = t[4] | (t[5] << 16);
  w.w = t[6] | (t[7] << 16);
  size_t off = (((size_t)g) * 64 + lane) * 8;    // elements
  *(uint4*)(Bp + off) = w;
}

// ---------- transpose small tail weights for coalesced reads ----------
__global__ __launch_bounds__(256) void prep_t(
    const float* __restrict__ Wq, const float* __restrict__ Wk,
    const float* __restrict__ Wc1, const float* __restrict__ Ws,
    float* __restrict__ WqT, float* __restrict__ WkT,
    float* __restrict__ Wc1T, float* __restrict__ WsT) {
  int t = blockIdx.x * 256 + threadIdx.x;   // 16384
  int h = t >> 6, dd = t & 63;
  WqT[dd * 256 + h]  = Wq[h * 64 + dd];
  WkT[dd * 256 + h]  = Wk[h * 64 + dd];
  Wc1T[dd * 256 + h] = Wc1[h * 64 + dd];
  WsT[h * 64 + dd]   = Ws[dd * 256 + h];
}

// ---------- main fused kernel ----------
// BM=64 rows, BN=256 cols, 4 waves 1M x 4N (wave = 64 rows x 64 cols).
// a1 is computed ONCE into LDS (fragment-linear, conflict-free), then the
// barrier-free K-loop is pure {4 global B loads + 4 ds_read A + 16 MFMA}
// per wave-stage, with 1-stage register double-buffer on both A and B.
__global__ __launch_bounds__(256, 3) void gemm_hcat(
    const float* __restrict__ x, const float* __restrict__ W1,
    const float* __restrict__ b1, const float* __restrict__ b2,
    const float* __restrict__ W3, const float* __restrict__ b3,
    const unsigned short* __restrict__ Bp, float* __restrict__ hcT) {
  __shared__ char As[32768];     // [s(8)][mi(4)][lane(64)][16B] a1 fragments
  __shared__ float P[4][64];

  int bid = blockIdx.x;
  int swz = (bid & 7) * 2048 + (bid >> 3);   // bijective XCD swizzle (16384 = 8*2048)
  int d = swz >> 8;
  int m0 = (swz & 255) << 6;

  int tid = threadIdx.x;
  int lane = tid & 63;
  int wn = tid >> 6;               // 1M x 4N: wave owns cols [wn*64, wn*64+64)
  int l15 = lane & 15;
  int koct = (lane >> 4) << 3;

  const unsigned short* BpD = Bp + (size_t)d * 65536;
  const float* W1d = W1 + d * Hn;
  const float* b1d = b1 + d * Hn;

  // ---- prologue: compute a1 tile (64 rows x 256 k) into LDS, fragment-linear ----
  {
    int mi = tid >> 6;             // reuse wave id as row-group id
    int row = (mi << 4) + l15;
    float xv = x[(size_t)(m0 + row) * Dn + d];
    char* dst = As + (mi << 10) + (lane << 4);
    #pragma unroll
    for (int s = 0; s < 8; ++s) {
      int k = s * 32 + koct;
      float4 wa = *(const float4*)(W1d + k);
      float4 wb = *(const float4*)(W1d + k + 4);
      float4 ba = *(const float4*)(b1d + k);
      float4 bb = *(const float4*)(b1d + k + 4);
      float v0 = fmaxf(fmaf(xv, wa.x, ba.x), 0.f);
      float v1 = fmaxf(fmaf(xv, wa.y, ba.y), 0.f);
      float v2 = fmaxf(fmaf(xv, wa.z, ba.z), 0.f);
      float v3 = fmaxf(fmaf(xv, wa.w, ba.w), 0.f);
      float v4 = fmaxf(fmaf(xv, wb.x, bb.x), 0.f);
      float v5 = fmaxf(fmaf(xv, wb.y, bb.y), 0.f);
      float v6 = fmaxf(fmaf(xv, wb.z, bb.z), 0.f);
      float v7 = fmaxf(fmaf(xv, wb.w, bb.w), 0.f);
      uint4 pk;
      asm("v_cvt_pk_bf16_f32 %0, %1, %2" : "=v"(pk.x) : "v"(v0), "v"(v1));
      asm("v_cvt_pk_bf16_f32 %0, %1, %2" : "=v"(pk.y) : "v"(v2), "v"(v3));
      asm("v_cvt_pk_bf16_f32 %0, %1, %2" : "=v"(pk.z) : "v"(v4), "v"(v5));
      asm("v_cvt_pk_bf16_f32 %0, %1, %2" : "=v"(pk.w) : "v"(v6), "v"(v7));
      *(uint4*)(dst + (s << 12)) = pk;
    }
  }
  __syncthreads();

  f32x4 acc[4][4] = {};

  #define LOADB(s, dst)                                                         \
    _Pragma("unroll")                                                           \
    for (int nj = 0; nj < 4; ++nj)                                              \
      dst[nj] = *(const bf16x8*)(BpD + ((((s) * 16 + (wn << 2) + nj) << 6) + lane) * 8);

  #define LOADA(s, dst)                                                         \
    _Pragma("unroll")                                                           \
    for (int mi = 0; mi < 4; ++mi)                                              \
      dst[mi] = *(const bf16x8*)(As + (((s) << 12) + (mi << 10)) + (lane << 4));

  bf16x8 bcur[4], acur[4];
  LOADB(0, bcur);
  LOADA(0, acur);

  #pragma unroll
  for (int s = 0; s < 8; ++s) {
    bf16x8 bnxt[4], anxt[4];
    if (s < 7) {
      LOADB(s + 1, bnxt);       // issue global loads first (latency cover)
      LOADA(s + 1, anxt);       // then LDS reads
    }

    __builtin_amdgcn_s_setprio(1);
    #pragma unroll
    for (int mi = 0; mi < 4; ++mi)
      #pragma unroll
      for (int nj = 0; nj < 4; ++nj)
        acc[mi][nj] = __builtin_amdgcn_mfma_f32_16x16x32_bf16(acur[mi], bcur[nj], acc[mi][nj], 0, 0, 0);
    __builtin_amdgcn_s_setprio(0);

    if (s < 7) {
      #pragma unroll
      for (int j = 0; j < 4; ++j) { bcur[j] = bnxt[j]; acur[j] = anxt[j]; }
    }
  }

  // epilogue: relu(+b2) . W3 over this wave's 64 columns, cross-wave reduce via P
  {
    const float* b2d = b2 + d * Hn;
    const float* W3d = W3 + d * Hn;
    float bv[4], wv[4];
    #pragma unroll
    for (int nj = 0; nj < 4; ++nj) {
      int col = ((wn << 2) + nj) * 16 + l15;
      bv[nj] = b2d[col];
      wv[nj] = W3d[col];
    }
    #pragma unroll
    for (int mi = 0; mi < 4; ++mi) {
      #pragma unroll
      for (int i = 0; i < 4; ++i) {
        float sv = 0.f;
        #pragma unroll
        for (int nj = 0; nj < 4; ++nj)
          sv += fmaxf(acc[mi][nj][i] + bv[nj], 0.f) * wv[nj];
        sv += __shfl_xor(sv, 1);
        sv += __shfl_xor(sv, 2);
        sv += __shfl_xor(sv, 4);
        sv += __shfl_xor(sv, 8);
        if (l15 == 0)
          P[wn][(mi << 4) + ((lane >> 4) << 2) + i] = sv;
      }
    }
  }
  __syncthreads();
  if (tid < 64)
    hcT[(size_t)d * Bn + m0 + tid] = P[0][tid] + P[1][tid] + P[2][tid] + P[3][tid] + b3[d];
}

// ---------- tail: attention fusion + cross MLP + g_func; 4 rows per wave ----------
__global__ __launch_bounds__(256) void fused_tail(
    const float* __restrict__ hcT, const float* __restrict__ WqT,
    const float* __restrict__ bq, const float* __restrict__ WkT,
    const float* __restrict__ bk, const float* __restrict__ WsT,
    const float* __restrict__ bs, const float* __restrict__ Wc1T,
    const float* __restrict__ bc1, const float* __restrict__ Wc2,
    const float* __restrict__ bc2, const float* __restrict__ Wg1,
    const float* __restrict__ bg1, const float* __restrict__ Wg2,
    const float* __restrict__ bg2, float* __restrict__ out) {
  __shared__ float hcs[4][4][64];
  __shared__ float ts[4][4][256];
  int wid = threadIdx.x >> 6;
  int lane = threadIdx.x & 63;
  int r0 = (blockIdx.x * 4 + wid) * 4;                 // 4 rows per wave
  float4 hc4 = *(const float4*)(hcT + (size_t)lane * Bn + r0);   // lane <-> feature d
  hcs[wid][0][lane] = hc4.x;
  hcs[wid][1][lane] = hc4.y;
  hcs[wid][2][lane] = hc4.z;
  hcs[wid][3][lane] = hc4.w;
  __syncthreads();

  float qv[4][4], kv[4][4], cv[4][4];
  #pragma unroll
  for (int j = 0; j < 4; ++j) {
    int h = lane + 64 * j;
    float bqv = bq[h], bkv = bk[h], bcv = bc1[h];
    #pragma unroll
    for (int r = 0; r < 4; ++r) { qv[r][j] = bqv; kv[r][j] = bkv; cv[r][j] = bcv; }
  }
  for (int d2 = 0; d2 < 64; ++d2) {
    float hv0 = hcs[wid][0][d2], hv1 = hcs[wid][1][d2];
    float hv2 = hcs[wid][2][d2], hv3 = hcs[wid][3][d2];
    #pragma unroll
    for (int j = 0; j < 4; ++j) {
      int h = lane + 64 * j;
      float wq = WqT[d2 * 256 + h], wk = WkT[d2 * 256 + h], wc = Wc1T[d2 * 256 + h];
      qv[0][j] = fmaf(wq, hv0, qv[0][j]); qv[1][j] = fmaf(wq, hv1, qv[1][j]);
      qv[2][j] = fmaf(wq, hv2, qv[2][j]); qv[3][j] = fmaf(wq, hv3, qv[3][j]);
      kv[0][j] = fmaf(wk, hv0, kv[0][j]); kv[1][j] = fmaf(wk, hv1, kv[1][j]);
      kv[2][j] = fmaf(wk, hv2, kv[2][j]); kv[3][j] = fmaf(wk, hv3, kv[3][j]);
      cv[0][j] = fmaf(wc, hv0, cv[0][j]); cv[1][j] = fmaf(wc, hv1, cv[1][j]);
      cv[2][j] = fmaf(wc, hv2, cv[2][j]); cv[3][j] = fmaf(wc, hv3, cv[3][j]);
    }
  }
  #pragma unroll
  for (int r = 0; r < 4; ++r)
    #pragma unroll
    for (int j = 0; j < 4; ++j)
      ts[wid][r][lane + 64 * j] = tanhf(qv[r][j] * kv[r][j]);
  __syncthreads();

  float sc[4];
  { float b = bs[lane]; sc[0] = b; sc[1] = b; sc[2] = b; sc[3] = b; }
  for (int h2 = 0; h2 < 256; ++h2) {
    float w = WsT[h2 * 64 + lane];
    sc[0] = fmaf(w, ts[wid][0][h2], sc[0]);
    sc[1] = fmaf(w, ts[wid][1][h2], sc[1]);
    sc[2] = fmaf(w, ts[wid][2][h2], sc[2]);
    sc[3] = fmaf(w, ts[wid][3][h2], sc[3]);
  }

  float hcr[4] = {hc4.x, hc4.y, hc4.z, hc4.w};
  float res[4];
  #pragma unroll
  for (int r = 0; r < 4; ++r) {
    float s = sc[r];
    float mx = s;
    #pragma unroll
    for (int off = 1; off < 64; off <<= 1) mx = fmaxf(mx, __shfl_xor(mx, off));
    float e = __expf(s - mx);
    float se = e;
    #pragma unroll
    for (int off = 1; off < 64; off <<= 1) se += __shfl_xor(se, off);
    float wgt = hcr[r] * (e / se);
    #pragma unroll
    for (int off = 1; off < 64; off <<= 1) wgt += __shfl_xor(wgt, off);
    float cp = 0.f;
    #pragma unroll
    for (int j = 0; j < 4; ++j) cp = fmaf(fmaxf(cv[r][j], 0.f), Wc2[lane + 64 * j], cp);
    #pragma unroll
    for (int off = 1; off < 64; off <<= 1) cp += __shfl_xor(cp, off);
    float comb = wgt + cp + bc2[0];
    float fp = 0.f;
    #pragma unroll
    for (int j = 0; j < 4; ++j) {
      int h = lane + 64 * j;
      fp = fmaf(fmaxf(fmaf(comb, Wg1[h], bg1[h]), 0.f), Wg2[h], fp);
    }
    #pragma unroll
    for (int off = 1; off < 64; off <<= 1) fp += __shfl_xor(fp, off);
    res[r] = fp + bg2[0];
  }
  if (lane == 0) {
    float4 o = make_float4(res[0], res[1], res[2], res[3]);
    *(float4*)(out + r0) = o;
  }
}

extern "C" void kernel_launch(void* const* d_in, const int* in_sizes, int n_in,
                              void* d_out, int out_size, void* d_ws, size_t ws_size,
                              hipStream_t stream) {
  const float* x   = (const float*)d_in[0];
  const float* W1  = (const float*)d_in[1];
  const float* b1  = (const float*)d_in[2];
  const float* W2  = (const float*)d_in[3];
  const float* b2  = (const float*)d_in[4];
  const float* W3  = (const float*)d_in[5];
  const float* b3  = (const float*)d_in[6];
  const float* Wq  = (const float*)d_in[7];
  const float* bq  = (const float*)d_in[8];
  const float* Wk  = (const float*)d_in[9];
  const float* bk  = (const float*)d_in[10];
  const float* Ws  = (const float*)d_in[11];
  const float* bs  = (const float*)d_in[12];
  const float* Wc1 = (const float*)d_in[13];
  const float* bc1 = (const float*)d_in[14];
  const float* Wc2 = (const float*)d_in[15];
  const float* bc2 = (const float*)d_in[16];
  const float* Wg1 = (const float*)d_in[17];
  const float* bg1 = (const float*)d_in[18];
  const float* Wg2 = (const float*)d_in[19];
  const float* bg2 = (const float*)d_in[20];

  unsigned short* Bp = (unsigned short*)d_ws;               // 8,388,608 B
  float* hcT  = (float*)((char*)d_ws + 8388608);            // 4,194,304 B
  float* WqT  = (float*)((char*)d_ws + 12582912);
  float* WkT  = WqT + 16384;
  float* Wc1T = WkT + 16384;
  float* WsT  = Wc1T + 16384;

  pack_w2<<<2048, 256, 0, stream>>>(W2, Bp);
  prep_t<<<64, 256, 0, stream>>>(Wq, Wk, Wc1, Ws, WqT, WkT, Wc1T, WsT);
  gemm_hcat<<<16384, 256, 0, stream>>>(x, W1, b1, b2, W3, b3, Bp, hcT);
  fused_tail<<<1024, 256, 0, stream>>>(hcT, WqT, bq, WkT, bk, WsT, bs, Wc1T, bc1,
                                       Wc2, bc2, Wg1, bg1, Wg2, bg2, (float*)d_out);
}

// Round 6
// 183.726 us; speedup vs baseline: 1.3668x; 1.1816x over previous
//
#include <hip/hip_runtime.h>
#include <stdint.h>

#define Bn 16384
#define Dn 64
#define Hn 256

typedef short bf16x8 __attribute__((ext_vector_type(8)));
typedef float f32x4 __attribute__((ext_vector_type(4)));

// ---------- x transpose: xT[d][row] (tiled, conflict-free) ----------
__global__ __launch_bounds__(256) void xpose(const float* __restrict__ x,
                                             float* __restrict__ xT) {
  __shared__ float tile[64][65];
  int t = threadIdx.x;
  int r0 = blockIdx.x * 64;
  int c = t & 63, rr = t >> 6;
  #pragma unroll
  for (int i = 0; i < 16; ++i)
    tile[rr + i * 4][c] = x[(size_t)(r0 + rr + i * 4) * Dn + c];
  __syncthreads();
  #pragma unroll
  for (int i = 0; i < 16; ++i)
    xT[(size_t)(rr + i * 4) * Bn + r0 + c] = tile[c][rr + i * 4];
}

// ---------- transpose small tail weights for coalesced reads ----------
__global__ __launch_bounds__(256) void prep_t(
    const float* __restrict__ Wq, const float* __restrict__ Wk,
    const float* __restrict__ Wc1, const float* __restrict__ Ws,
    float* __restrict__ WqT, float* __restrict__ WkT,
    float* __restrict__ Wc1T, float* __restrict__ WsT) {
  int t = blockIdx.x * 256 + threadIdx.x;   // 16384
  int h = t >> 6, dd = t & 63;
  WqT[dd * 256 + h]  = Wq[h * 64 + dd];
  WkT[dd * 256 + h]  = Wk[h * 64 + dd];
  Wc1T[dd * 256 + h] = Wc1[h * 64 + dd];
  WsT[h * 64 + dd]   = Ws[dd * 256 + h];
}

// ---------- persistent fused GEMM ----------
// 512 blocks = 64 d x 8 chunks, 2 blocks/CU. 512 threads = 8 waves (2M x 4N,
// wave tile 32x64). Per block: B (W2) gathered ONCE into 128 VGPR/wave; then
// 32 m-tiles of 64 rows: a1 streamed through a 2x32KB LDS double-buffer
// (wave w writes stage-w fragments for tile t+1 inside tile t's K-loop),
// one barrier per m-tile. Swapped-operand MFMA gives a2^T so rows sit in
// lane&15: epilogue = in-register relu.W3 dot + 2 shfl + tiny P reduce.
// b2 is folded into the accumulator init.
__global__ __launch_bounds__(512, 2) void gemm_hcat(
    const float* __restrict__ xT, const float* __restrict__ W1,
    const float* __restrict__ b1, const float* __restrict__ W2,
    const float* __restrict__ b2, const float* __restrict__ W3,
    const float* __restrict__ b3, float* __restrict__ hcT) {
  __shared__ char As[2][32768];   // a1 dbuf: [stage(8)][gm(4)][lane(64)][16B]
  __shared__ float P[2][4][64];   // cross-wn partials, dbuf'd

  int bid = blockIdx.x;
  int j = bid >> 3;
  int d = (bid & 7) * 8 + (j & 7);   // 8 d per XCD -> W2 slice L2-resident
  int base = (j >> 3) * 2048;        // chunk of 2048 rows

  int tid = threadIdx.x;
  int lane = tid & 63;
  int w = tid >> 6;                  // wave id; also the a1 stage it writes
  int wm = w >> 2, wn = w & 3;       // 2M x 4N, wave tile 32 rows x 64 cols
  int l15 = lane & 15;
  int g = lane >> 4;                 // k-octet group in fragment
  int ko = w * 4 + g;                // this thread's k-octet (0..31)

  const float* W1d = W1 + d * Hn;
  const float* b1d = b1 + d * Hn;
  const float* W2d = W2 + (size_t)d * Hn * Hn;
  const float* xTd = xT + (size_t)d * Bn + base;

  // one-time register preloads -------------------------------------------
  float4 w1a = *(const float4*)(W1d + ko * 8);
  float4 w1b = *(const float4*)(W1d + ko * 8 + 4);
  float4 b1a = *(const float4*)(b1d + ko * 8);
  float4 b1b = *(const float4*)(b1d + ko * 8 + 4);

  float4 bvf[4], wvf[4];
  #pragma unroll
  for (int nj = 0; nj < 4; ++nj) {
    int col = wn * 64 + nj * 16 + g * 4;
    bvf[nj] = *(const float4*)(b2 + d * Hn + col);
    wvf[nj] = *(const float4*)(W3 + d * Hn + col);
  }

  // gather B fragments straight from W2 (fp32) -> bf16 regs, once
  bf16x8 breg[32];
  #pragma unroll
  for (int s = 0; s < 8; ++s)
    #pragma unroll
    for (int nj = 0; nj < 4; ++nj) {
      const float* src = W2d + (size_t)(s * 32 + g * 8) * Hn + wn * 64 + nj * 16 + l15;
      float u0 = src[0],        u1 = src[Hn],       u2 = src[2 * Hn], u3 = src[3 * Hn];
      float u4 = src[4 * Hn],   u5 = src[5 * Hn],   u6 = src[6 * Hn], u7 = src[7 * Hn];
      union { uint4 u; bf16x8 v; } pk;
      asm("v_cvt_pk_bf16_f32 %0, %1, %2" : "=v"(pk.u.x) : "v"(u0), "v"(u1));
      asm("v_cvt_pk_bf16_f32 %0, %1, %2" : "=v"(pk.u.y) : "v"(u2), "v"(u3));
      asm("v_cvt_pk_bf16_f32 %0, %1, %2" : "=v"(pk.u.z) : "v"(u4), "v"(u5));
      asm("v_cvt_pk_bf16_f32 %0, %1, %2" : "=v"(pk.u.w) : "v"(u6), "v"(u7));
      breg[s * 4 + nj] = pk.v;
    }

  // a1 fragment compute+store: stage = w, row-group gm, rows gm*16+l15
  #define A1CHUNK(wb, gm, xv)                                                   \
    {                                                                           \
      float v0 = fmaxf(fmaf((xv), w1a.x, b1a.x), 0.f);                          \
      float v1 = fmaxf(fmaf((xv), w1a.y, b1a.y), 0.f);                          \
      float v2 = fmaxf(fmaf((xv), w1a.z, b1a.z), 0.f);                          \
      float v3 = fmaxf(fmaf((xv), w1a.w, b1a.w), 0.f);                          \
      float v4 = fmaxf(fmaf((xv), w1b.x, b1b.x), 0.f);                          \
      float v5 = fmaxf(fmaf((xv), w1b.y, b1b.y), 0.f);                          \
      float v6 = fmaxf(fmaf((xv), w1b.z, b1b.z), 0.f);                          \
      float v7 = fmaxf(fmaf((xv), w1b.w, b1b.w), 0.f);                          \
      uint4 pk;                                                                 \
      asm("v_cvt_pk_bf16_f32 %0, %1, %2" : "=v"(pk.x) : "v"(v0), "v"(v1));      \
      asm("v_cvt_pk_bf16_f32 %0, %1, %2" : "=v"(pk.y) : "v"(v2), "v"(v3));      \
      asm("v_cvt_pk_bf16_f32 %0, %1, %2" : "=v"(pk.z) : "v"(v4), "v"(v5));      \
      asm("v_cvt_pk_bf16_f32 %0, %1, %2" : "=v"(pk.w) : "v"(v6), "v"(v7));      \
      *(uint4*)((wb) + (w * 4 + (gm)) * 1024 + lane * 16) = pk;                 \
    }

  // prologue: a1 for tile 0
  {
    #pragma unroll
    for (int gm = 0; gm < 4; ++gm) {
      float xv = xTd[gm * 16 + l15];
      A1CHUNK(As[0], gm, xv);
    }
  }
  __syncthreads();

  float b3d = b3[d];
  for (int t = 0; t < 32; ++t) {
    int p = t & 1;
    const char* rb = As[p];
    char* wb = As[p ^ 1];
    bool pre = (t < 31);
    float xn[4];
    if (pre) {
      #pragma unroll
      for (int gm = 0; gm < 4; ++gm) xn[gm] = xTd[(t + 1) * 64 + gm * 16 + l15];
    }

    f32x4 acc[2][4];   // b2 folded into init
    #pragma unroll
    for (int mi = 0; mi < 2; ++mi)
      #pragma unroll
      for (int nj = 0; nj < 4; ++nj) {
        f32x4 iv = {bvf[nj].x, bvf[nj].y, bvf[nj].z, bvf[nj].w};
        acc[mi][nj] = iv;
      }

    #pragma unroll
    for (int s = 0; s < 8; ++s) {
      bf16x8 af0 = *(const bf16x8*)(rb + (s * 4 + wm * 2) * 1024 + lane * 16);
      bf16x8 af1 = *(const bf16x8*)(rb + (s * 4 + wm * 2 + 1) * 1024 + lane * 16);
      if (pre && s < 4) { A1CHUNK(wb, s, xn[s]); }   // next tile's a1, interleaved
      __builtin_amdgcn_s_setprio(1);
      #pragma unroll
      for (int nj = 0; nj < 4; ++nj) {
        acc[0][nj] = __builtin_amdgcn_mfma_f32_16x16x32_bf16(breg[s * 4 + nj], af0, acc[0][nj], 0, 0, 0);
        acc[1][nj] = __builtin_amdgcn_mfma_f32_16x16x32_bf16(breg[s * 4 + nj], af1, acc[1][nj], 0, 0, 0);
      }
      __builtin_amdgcn_s_setprio(0);
    }

    // epilogue: relu . W3 (rows live in l15; cols in per-lane elems + g + nj)
    float* Pb = (float*)P[p];
    #pragma unroll
    for (int mi = 0; mi < 2; ++mi) {
      float ph = 0.f;
      #pragma unroll
      for (int nj = 0; nj < 4; ++nj) {
        ph = fmaf(fmaxf(acc[mi][nj][0], 0.f), wvf[nj].x, ph);
        ph = fmaf(fmaxf(acc[mi][nj][1], 0.f), wvf[nj].y, ph);
        ph = fmaf(fmaxf(acc[mi][nj][2], 0.f), wvf[nj].z, ph);
        ph = fmaf(fmaxf(acc[mi][nj][3], 0.f), wvf[nj].w, ph);
      }
      ph += __shfl_xor(ph, 16);
      ph += __shfl_xor(ph, 32);
      if (lane < 16) Pb[wn * 64 + wm * 32 + mi * 16 + l15] = ph;
    }
    __syncthreads();
    if (tid < 64)
      hcT[(size_t)d * Bn + base + t * 64 + tid] =
          Pb[tid] + Pb[64 + tid] + Pb[128 + tid] + Pb[192 + tid] + b3d;
  }
  #undef A1CHUNK
}

// ---------- tail: attention fusion + cross MLP + g_func; 4 rows per wave ----------
__global__ __launch_bounds__(256) void fused_tail(
    const float* __restrict__ hcT, const float* __restrict__ WqT,
    const float* __restrict__ bq, const float* __restrict__ WkT,
    const float* __restrict__ bk, const float* __restrict__ WsT,
    const float* __restrict__ bs, const float* __restrict__ Wc1T,
    const float* __restrict__ bc1, const float* __restrict__ Wc2,
    const float* __restrict__ bc2, const float* __restrict__ Wg1,
    const float* __restrict__ bg1, const float* __restrict__ Wg2,
    const float* __restrict__ bg2, float* __restrict__ out) {
  __shared__ float hcs[4][4][64];
  __shared__ float ts[4][4][256];
  int wid = threadIdx.x >> 6;
  int lane = threadIdx.x & 63;
  int r0 = (blockIdx.x * 4 + wid) * 4;                 // 4 rows per wave
  float4 hc4 = *(const float4*)(hcT + (size_t)lane * Bn + r0);   // lane <-> feature d
  hcs[wid][0][lane] = hc4.x;
  hcs[wid][1][lane] = hc4.y;
  hcs[wid][2][lane] = hc4.z;
  hcs[wid][3][lane] = hc4.w;
  __syncthreads();

  float qv[4][4], kv[4][4], cv[4][4];
  #pragma unroll
  for (int j = 0; j < 4; ++j) {
    int h = lane + 64 * j;
    float bqv = bq[h], bkv = bk[h], bcv = bc1[h];
    #pragma unroll
    for (int r = 0; r < 4; ++r) { qv[r][j] = bqv; kv[r][j] = bkv; cv[r][j] = bcv; }
  }
  for (int d2 = 0; d2 < 64; ++d2) {
    float hv0 = hcs[wid][0][d2], hv1 = hcs[wid][1][d2];
    float hv2 = hcs[wid][2][d2], hv3 = hcs[wid][3][d2];
    #pragma unroll
    for (int j = 0; j < 4; ++j) {
      int h = lane + 64 * j;
      float wq = WqT[d2 * 256 + h], wk = WkT[d2 * 256 + h], wc = Wc1T[d2 * 256 + h];
      qv[0][j] = fmaf(wq, hv0, qv[0][j]); qv[1][j] = fmaf(wq, hv1, qv[1][j]);
      qv[2][j] = fmaf(wq, hv2, qv[2][j]); qv[3][j] = fmaf(wq, hv3, qv[3][j]);
      kv[0][j] = fmaf(wk, hv0, kv[0][j]); kv[1][j] = fmaf(wk, hv1, kv[1][j]);
      kv[2][j] = fmaf(wk, hv2, kv[2][j]); kv[3][j] = fmaf(wk, hv3, kv[3][j]);
      cv[0][j] = fmaf(wc, hv0, cv[0][j]); cv[1][j] = fmaf(wc, hv1, cv[1][j]);
      cv[2][j] = fmaf(wc, hv2, cv[2][j]); cv[3][j] = fmaf(wc, hv3, cv[3][j]);
    }
  }
  #pragma unroll
  for (int r = 0; r < 4; ++r)
    #pragma unroll
    for (int j = 0; j < 4; ++j)
      ts[wid][r][lane + 64 * j] = tanhf(qv[r][j] * kv[r][j]);
  __syncthreads();

  float sc[4];
  { float b = bs[lane]; sc[0] = b; sc[1] = b; sc[2] = b; sc[3] = b; }
  for (int h2 = 0; h2 < 256; ++h2) {
    float w = WsT[h2 * 64 + lane];
    sc[0] = fmaf(w, ts[wid][0][h2], sc[0]);
    sc[1] = fmaf(w, ts[wid][1][h2], sc[1]);
    sc[2] = fmaf(w, ts[wid][2][h2], sc[2]);
    sc[3] = fmaf(w, ts[wid][3][h2], sc[3]);
  }

  float hcr[4] = {hc4.x, hc4.y, hc4.z, hc4.w};
  float res[4];
  #pragma unroll
  for (int r = 0; r < 4; ++r) {
    float s = sc[r];
    float mx = s;
    #pragma unroll
    for (int off = 1; off < 64; off <<= 1) mx = fmaxf(mx, __shfl_xor(mx, off));
    float e = __expf(s - mx);
    float se = e;
    #pragma unroll
    for (int off = 1; off < 64; off <<= 1) se += __shfl_xor(se, off);
    float wgt = hcr[r] * (e / se);
    #pragma unroll
    for (int off = 1; off < 64; off <<= 1) wgt += __shfl_xor(wgt, off);
    float cp = 0.f;
    #pragma unroll
    for (int j = 0; j < 4; ++j) cp = fmaf(fmaxf(cv[r][j], 0.f), Wc2[lane + 64 * j], cp);
    #pragma unroll
    for (int off = 1; off < 64; off <<= 1) cp += __shfl_xor(cp, off);
    float comb = wgt + cp + bc2[0];
    float fp = 0.f;
    #pragma unroll
    for (int j = 0; j < 4; ++j) {
      int h = lane + 64 * j;
      fp = fmaf(fmaxf(fmaf(comb, Wg1[h], bg1[h]), 0.f), Wg2[h], fp);
    }
    #pragma unroll
    for (int off = 1; off < 64; off <<= 1) fp += __shfl_xor(fp, off);
    res[r] = fp + bg2[0];
  }
  if (lane == 0) {
    float4 o = make_float4(res[0], res[1], res[2], res[3]);
    *(float4*)(out + r0) = o;
  }
}

extern "C" void kernel_launch(void* const* d_in, const int* in_sizes, int n_in,
                              void* d_out, int out_size, void* d_ws, size_t ws_size,
                              hipStream_t stream) {
  const float* x   = (const float*)d_in[0];
  const float* W1  = (const float*)d_in[1];
  const float* b1  = (const float*)d_in[2];
  const float* W2  = (const float*)d_in[3];
  const float* b2  = (const float*)d_in[4];
  const float* W3  = (const float*)d_in[5];
  const float* b3  = (const float*)d_in[6];
  const float* Wq  = (const float*)d_in[7];
  const float* bq  = (const float*)d_in[8];
  const float* Wk  = (const float*)d_in[9];
  const float* bk  = (const float*)d_in[10];
  const float* Ws  = (const float*)d_in[11];
  const float* bs  = (const float*)d_in[12];
  const float* Wc1 = (const float*)d_in[13];
  const float* bc1 = (const float*)d_in[14];
  const float* Wc2 = (const float*)d_in[15];
  const float* bc2 = (const float*)d_in[16];
  const float* Wg1 = (const float*)d_in[17];
  const float* bg1 = (const float*)d_in[18];
  const float* Wg2 = (const float*)d_in[19];
  const float* bg2 = (const float*)d_in[20];

  float* hcT  = (float*)d_ws;                               // 4 MB
  float* xT   = (float*)((char*)d_ws + 4194304);            // 4 MB
  float* WqT  = (float*)((char*)d_ws + 8388608);
  float* WkT  = WqT + 16384;
  float* Wc1T = WkT + 16384;
  float* WsT  = Wc1T + 16384;

  xpose<<<256, 256, 0, stream>>>(x, xT);
  prep_t<<<64, 256, 0, stream>>>(Wq, Wk, Wc1, Ws, WqT, WkT, Wc1T, WsT);
  gemm_hcat<<<512, 512, 0, stream>>>(xT, W1, b1, W2, b2, W3, b3, hcT);
  fused_tail<<<1024, 256, 0, stream>>>(hcT, WqT, bq, WkT, bk, WsT, bs, Wc1T, bc1,
                                       Wc2, bc2, Wg1, bg1, Wg2, bg2, (float*)d_out);
}